// Round 1
// baseline (7548.757 us; speedup 1.0000x reference)
//
#include <hip/hip_runtime.h>
#include <math.h>

#define NNODES 50000
#define NEDGES 800000
#define EMB 256
#define HID 512

// ---------------- generic tiled fp32 GEMM: C = act(acc*C + A@B + bias) ----------------
#define BM 64
#define BN 64
#define BK 16

__global__ __launch_bounds__(256) void gemm_kernel(
    const float* __restrict__ A, int lda,
    const float* __restrict__ B, int ldb,
    float* __restrict__ C, int ldc,
    const float* __restrict__ bias,
    int M, int N, int K, int accumulate, int act)
{
    __shared__ float As[BK][BM];   // As[k][m]
    __shared__ float Bs[BK][BN];   // Bs[k][n]
    const int bm = blockIdx.y * BM;
    const int bn = blockIdx.x * BN;
    const int tid = threadIdx.x;           // 0..255
    const int tx = tid & 15;               // 0..15
    const int ty = tid >> 4;               // 0..15

    float acc[4][4] = {};

    for (int k0 = 0; k0 < K; k0 += BK) {
        // load A tile (BM x BK)
        for (int l = tid; l < BM * BK; l += 256) {
            int m = l / BK, k = l % BK;
            int gr = bm + m, gc = k0 + k;
            As[k][m] = (gr < M && gc < K) ? A[(size_t)gr * lda + gc] : 0.0f;
        }
        // load B tile (BK x BN)
        for (int l = tid; l < BK * BN; l += 256) {
            int k = l / BN, n = l % BN;
            int gr = k0 + k, gc = bn + n;
            Bs[k][n] = (gr < K && gc < N) ? B[(size_t)gr * ldb + gc] : 0.0f;
        }
        __syncthreads();
#pragma unroll
        for (int k = 0; k < BK; ++k) {
            float a[4], b[4];
#pragma unroll
            for (int i = 0; i < 4; ++i) a[i] = As[k][ty * 4 + i];
#pragma unroll
            for (int j = 0; j < 4; ++j) b[j] = Bs[k][tx * 4 + j];
#pragma unroll
            for (int i = 0; i < 4; ++i)
#pragma unroll
                for (int j = 0; j < 4; ++j)
                    acc[i][j] += a[i] * b[j];
        }
        __syncthreads();
    }

#pragma unroll
    for (int i = 0; i < 4; ++i) {
        int r = bm + ty * 4 + i;
        if (r >= M) continue;
#pragma unroll
        for (int j = 0; j < 4; ++j) {
            int c = bn + tx * 4 + j;
            if (c >= N) continue;
            float v = acc[i][j];
            if (accumulate) v += C[(size_t)r * ldc + c];
            if (bias) v += bias[c];
            if (act) v = v > 0.0f ? v : 0.01f * v;
            C[(size_t)r * ldc + c] = v;
        }
    }
}

// ---------------- degree / dinv ----------------
__global__ void deg_kernel(const int* __restrict__ dst, float* __restrict__ deg, int nE)
{
    int e = blockIdx.x * 256 + threadIdx.x;
    if (e < nE) atomicAdd(&deg[dst[e]], 1.0f);
}

__global__ void dinv_kernel(float* __restrict__ deg, int n)
{
    int i = blockIdx.x * 256 + threadIdx.x;
    if (i < n) deg[i] = rsqrtf(deg[i] + 1.0f);   // +1 for self loop
}

// ---------------- edge scatter: agg[dst] += t[src] * dinv[src]*dinv[dst] ----------------
__global__ __launch_bounds__(256) void scatter_kernel(
    const float* __restrict__ t, const int* __restrict__ src, const int* __restrict__ dst,
    const float* __restrict__ dinv, float* __restrict__ agg, int nE)
{
    int e = blockIdx.x * 4 + (threadIdx.x >> 6);
    if (e >= nE) return;
    int lane = threadIdx.x & 63;
    int s = src[e], d = dst[e];
    float w = dinv[s] * dinv[d];
    const float4* ts = (const float4*)(t + (size_t)s * EMB);
    float4 v = ts[lane];
    float* o = agg + (size_t)d * EMB + lane * 4;
    atomicAdd(o + 0, v.x * w);
    atomicAdd(o + 1, v.y * w);
    atomicAdd(o + 2, v.z * w);
    atomicAdd(o + 3, v.w * w);
}

// ---------------- conv epilogue: out = lrelu(agg + t*dinv^2 + bias) ----------------
__global__ __launch_bounds__(256) void conv_epilogue(
    const float* __restrict__ agg, const float* __restrict__ t,
    const float* __restrict__ dinv, const float* __restrict__ bias,
    float* __restrict__ out, int ldc)
{
    int i = blockIdx.x;
    int j = threadIdx.x;
    float di = dinv[i];
    float v = agg[(size_t)i * EMB + j] + t[(size_t)i * EMB + j] * di * di + bias[j];
    out[(size_t)i * ldc + j] = v > 0.0f ? v : 0.01f * v;
}

// ---------------- final: s_ci = sigmoid(s @ Wl2 + bl2), replicate x3 ----------------
__global__ __launch_bounds__(256) void rowdot_sigmoid(
    const float* __restrict__ s, const float* __restrict__ w, const float* __restrict__ b,
    float* __restrict__ out, int n)
{
    int row = blockIdx.x * 4 + (threadIdx.x >> 6);
    int lane = threadIdx.x & 63;
    if (row >= n) return;
    const float4* sr = (const float4*)(s + (size_t)row * 256);
    const float4* wr = (const float4*)w;
    float4 a = sr[lane], c = wr[lane];
    float p = a.x * c.x + a.y * c.y + a.z * c.z + a.w * c.w;
#pragma unroll
    for (int off = 32; off > 0; off >>= 1) p += __shfl_down(p, off);
    if (lane == 0) {
        float v = 1.0f / (1.0f + expf(-(p + b[0])));
        out[row] = v;
        out[n + row] = v;
        out[2 * n + row] = v;
    }
}

extern "C" void kernel_launch(void* const* d_in, const int* in_sizes, int n_in,
                              void* d_out, int out_size, void* d_ws, size_t ws_size,
                              hipStream_t stream)
{
    const float* discrete_x = (const float*)d_in[0];
    const float* continous_x = (const float*)d_in[1];
    const float* Wd  = (const float*)d_in[2];  const float* bd  = (const float*)d_in[3];
    const float* Wc1 = (const float*)d_in[4];  const float* bc1 = (const float*)d_in[5];
    const float* Wc2 = (const float*)d_in[6];  const float* bc2 = (const float*)d_in[7];
    const float* Wg0 = (const float*)d_in[8];  const float* bg0 = (const float*)d_in[9];
    const float* Wg1 = (const float*)d_in[10]; const float* bg1 = (const float*)d_in[11];
    const float* Wg2 = (const float*)d_in[12]; const float* bg2 = (const float*)d_in[13];
    const float* Wf  = (const float*)d_in[14]; const float* bf  = (const float*)d_in[15];
    const float* Wl1 = (const float*)d_in[16]; const float* bl1 = (const float*)d_in[17];
    const float* Wl2 = (const float*)d_in[18]; const float* bl2 = (const float*)d_in[19];
    const int* edge_index = (const int*)d_in[20];
    const int* src = edge_index;
    const int* dst = edge_index + NEDGES;

    float* out = (float*)d_out;
    float* ws = (float*)d_ws;

    // workspace layout (floats)
    float* dinv = ws;                                     // NNODES (rounded to 50048)
    float* xcat = ws + 50048;                             // NNODES * 1024
    float* xg   = xcat + (size_t)NNODES * 1024;           // NNODES * 256
    float* tbuf = xg   + (size_t)NNODES * EMB;            // NNODES * 256
    float* agg  = tbuf + (size_t)NNODES * EMB;            // NNODES * 256  (reused as sbuf)
    float* sbuf = agg;                                    // reuse after conv2

    float* h_out  = out + 3 * (size_t)NNODES;             // NNODES * 512
    float* h_out2 = h_out + (size_t)NNODES * HID;

    dim3 blk(256);
    auto gemm = [&](const float* A, int lda, const float* B, int ldb, float* C, int ldc,
                    const float* bias, int M, int N, int K, int accum, int act) {
        dim3 grid((N + BN - 1) / BN, (M + BM - 1) / BM);
        hipLaunchKernelGGL(gemm_kernel, grid, blk, 0, stream,
                           A, lda, B, ldb, C, ldc, bias, M, N, K, accum, act);
    };

    // degrees -> dinv (in place)
    hipMemsetAsync(dinv, 0, NNODES * sizeof(float), stream);
    hipLaunchKernelGGL(deg_kernel, dim3((NEDGES + 255) / 256), blk, 0, stream, dst, dinv, NEDGES);
    hipLaunchKernelGGL(dinv_kernel, dim3((NNODES + 255) / 256), blk, 0, stream, dinv, NNODES);

    // embeddings directly into concat buffer [N, 1024] = [x_d | x_c1 | x_c2 | x_g2]
    gemm(discrete_x,      64, Wd,  EMB, xcat + 0,   1024, bd,  NNODES, EMB, 64, 0, 1);
    gemm(continous_x,     39, Wc1, EMB, xcat + 256, 1024, bc1, NNODES, EMB, 13, 0, 1);
    gemm(continous_x + 13,39, Wc2, EMB, xcat + 512, 1024, bc2, NNODES, EMB, 13, 0, 1);
    gemm(discrete_x,      64, Wg0, EMB, xg,          EMB, bg0, NNODES, EMB, 64, 0, 1);

    // GCN conv 1: t = xg @ Wg1 ; agg = scatter ; xg = lrelu(agg + t*dinv^2 + bg1)
    gemm(xg, EMB, Wg1, EMB, tbuf, EMB, nullptr, NNODES, EMB, EMB, 0, 0);
    hipMemsetAsync(agg, 0, (size_t)NNODES * EMB * sizeof(float), stream);
    hipLaunchKernelGGL(scatter_kernel, dim3((NEDGES + 3) / 4), blk, 0, stream,
                       tbuf, src, dst, dinv, agg, NEDGES);
    hipLaunchKernelGGL(conv_epilogue, dim3(NNODES), blk, 0, stream, agg, tbuf, dinv, bg1, xg, EMB);

    // GCN conv 2 -> write into concat column 768
    gemm(xg, EMB, Wg2, EMB, tbuf, EMB, nullptr, NNODES, EMB, EMB, 0, 0);
    hipMemsetAsync(agg, 0, (size_t)NNODES * EMB * sizeof(float), stream);
    hipLaunchKernelGGL(scatter_kernel, dim3((NEDGES + 3) / 4), blk, 0, stream,
                       tbuf, src, dst, dinv, agg, NEDGES);
    hipLaunchKernelGGL(conv_epilogue, dim3(NNODES), blk, 0, stream, agg, tbuf, dinv, bg2, xcat + 768, 1024);

    // h_ci = lrelu(xcat @ Wf + bf) -> directly into d_out
    gemm(xcat, 1024, Wf, HID, h_out, HID, bf, NNODES, HID, 1024, 0, 1);
    hipMemcpyAsync(h_out2, h_out, (size_t)NNODES * HID * sizeof(float),
                   hipMemcpyDeviceToDevice, stream);

    // s = lrelu(h @ Wl1 + bl1)
    gemm(h_out, HID, Wl1, 256, sbuf, 256, bl1, NNODES, 256, HID, 0, 1);

    // s_ci = sigmoid(s @ Wl2 + bl2) -> out[0:N], out[N:2N], out[2N:3N]
    hipLaunchKernelGGL(rowdot_sigmoid, dim3((NNODES + 3) / 4), blk, 0, stream,
                       sbuf, Wl2, bl2, out, NNODES);
}

// Round 2
// 2254.313 us; speedup vs baseline: 3.3486x; 3.3486x over previous
//
#include <hip/hip_runtime.h>
#include <math.h>

#define NNODES 50000
#define NEDGES 800000
#define EMB 256
#define HID 512

// ---------------- generic tiled fp32 GEMM: C = act(A@B + bias), optional dual store ----
#define BM 64
#define BN 64
#define BK 16

__global__ __launch_bounds__(256) void gemm_kernel(
    const float* __restrict__ A, int lda,
    const float* __restrict__ B, int ldb,
    float* __restrict__ C, int ldc,
    float* __restrict__ C2,
    const float* __restrict__ bias,
    int M, int N, int K, int act)
{
    __shared__ float As[BK][BM];   // As[k][m]
    __shared__ float Bs[BK][BN];   // Bs[k][n]
    const int bm = blockIdx.y * BM;
    const int bn = blockIdx.x * BN;
    const int tid = threadIdx.x;           // 0..255
    const int tx = tid & 15;               // 0..15
    const int ty = tid >> 4;               // 0..15

    float acc[4][4] = {};

    for (int k0 = 0; k0 < K; k0 += BK) {
        for (int l = tid; l < BM * BK; l += 256) {
            int m = l / BK, k = l % BK;
            int gr = bm + m, gc = k0 + k;
            As[k][m] = (gr < M && gc < K) ? A[(size_t)gr * lda + gc] : 0.0f;
        }
        for (int l = tid; l < BK * BN; l += 256) {
            int k = l / BN, n = l % BN;
            int gr = k0 + k, gc = bn + n;
            Bs[k][n] = (gr < K && gc < N) ? B[(size_t)gr * ldb + gc] : 0.0f;
        }
        __syncthreads();
#pragma unroll
        for (int k = 0; k < BK; ++k) {
            float a[4], b[4];
#pragma unroll
            for (int i = 0; i < 4; ++i) a[i] = As[k][ty * 4 + i];
#pragma unroll
            for (int j = 0; j < 4; ++j) b[j] = Bs[k][tx * 4 + j];
#pragma unroll
            for (int i = 0; i < 4; ++i)
#pragma unroll
                for (int j = 0; j < 4; ++j)
                    acc[i][j] += a[i] * b[j];
        }
        __syncthreads();
    }

#pragma unroll
    for (int i = 0; i < 4; ++i) {
        int r = bm + ty * 4 + i;
        if (r >= M) continue;
#pragma unroll
        for (int j = 0; j < 4; ++j) {
            int c = bn + tx * 4 + j;
            if (c >= N) continue;
            float v = acc[i][j];
            if (bias) v += bias[c];
            if (act) v = v > 0.0f ? v : 0.01f * v;
            C[(size_t)r * ldc + c] = v;
            if (C2) C2[(size_t)r * ldc + c] = v;
        }
    }
}

// ---------------- CSR build ----------------
__global__ void count_deg(const int* __restrict__ dst, int* __restrict__ deg, int nE)
{
    int e = blockIdx.x * 256 + threadIdx.x;
    if (e < nE) atomicAdd(&deg[dst[e]], 1);
}

__global__ void dinv_kernel(const int* __restrict__ deg, float* __restrict__ dinv, int n)
{
    int i = blockIdx.x * 256 + threadIdx.x;
    if (i < n) dinv[i] = rsqrtf((float)deg[i] + 1.0f);   // +1 for self loop
}

// exclusive scan, 1024 elements per block
__global__ __launch_bounds__(256) void scan1(const int* __restrict__ deg,
                                             int* __restrict__ excl,
                                             int* __restrict__ blocksum, int n)
{
    __shared__ int tsum[256];
    int base = blockIdx.x * 1024;
    int t = threadIdx.x;
    int v[4], s = 0;
#pragma unroll
    for (int j = 0; j < 4; ++j) {
        int idx = base + t * 4 + j;
        v[j] = (idx < n) ? deg[idx] : 0;
        s += v[j];
    }
    tsum[t] = s;
    __syncthreads();
    for (int off = 1; off < 256; off <<= 1) {
        int x = (t >= off) ? tsum[t - off] : 0;
        __syncthreads();
        tsum[t] += x;
        __syncthreads();
    }
    int toff = tsum[t] - s;   // exclusive offset of this thread within block
    int run = 0;
#pragma unroll
    for (int j = 0; j < 4; ++j) {
        int idx = base + t * 4 + j;
        if (idx < n) excl[idx] = toff + run;
        run += v[j];
    }
    if (t == 255) blocksum[blockIdx.x] = tsum[255];
}

__global__ void scan2(int* __restrict__ blocksum, int nb)
{
    if (threadIdx.x == 0 && blockIdx.x == 0) {
        int run = 0;
        for (int i = 0; i < nb; ++i) {
            int v = blocksum[i];
            blocksum[i] = run;
            run += v;
        }
    }
}

__global__ void scan3(int* __restrict__ rowptr, int* __restrict__ cursor,
                      const int* __restrict__ excl, const int* __restrict__ blocksum, int n)
{
    int idx = blockIdx.x * 256 + threadIdx.x;
    if (idx < n) {
        int v = excl[idx] + blocksum[idx >> 10];
        rowptr[idx] = v;
        cursor[idx] = v;
    }
    if (idx == 0) rowptr[n] = NEDGES;
}

__global__ void fill_csr(const int* __restrict__ src, const int* __restrict__ dst,
                         const float* __restrict__ dinv, int* __restrict__ cursor,
                         int* __restrict__ src_sorted, float* __restrict__ w_sorted, int nE)
{
    int e = blockIdx.x * 256 + threadIdx.x;
    if (e >= nE) return;
    int s = src[e], d = dst[e];
    int pos = atomicAdd(&cursor[d], 1);
    src_sorted[pos] = s;
    w_sorted[pos] = dinv[s] * dinv[d];
}

// ---------------- fused GCN aggregation: out = lrelu(sum_e w*t[src] + t[i]*dinv^2 + b) --
__global__ __launch_bounds__(256) void gather_conv(
    const float* __restrict__ t, const int* __restrict__ rowptr,
    const int* __restrict__ src_sorted, const float* __restrict__ w_sorted,
    const float* __restrict__ dinv, const float* __restrict__ bias,
    float* __restrict__ out, int ldc)
{
    int node = blockIdx.x * 4 + (threadIdx.x >> 6);
    if (node >= NNODES) return;
    int lane = threadIdx.x & 63;
    int p0 = rowptr[node], p1 = rowptr[node + 1];
    const float4* tv = (const float4*)t;
    float4 acc = {0.f, 0.f, 0.f, 0.f};
    for (int p = p0; p < p1; ++p) {
        int s = src_sorted[p];
        float w = w_sorted[p];
        float4 v = tv[(size_t)s * 64 + lane];
        acc.x += v.x * w; acc.y += v.y * w; acc.z += v.z * w; acc.w += v.w * w;
    }
    float di = dinv[node];
    float w2 = di * di;
    float4 self = tv[(size_t)node * 64 + lane];
    float4 b = ((const float4*)bias)[lane];
    acc.x += self.x * w2 + b.x;
    acc.y += self.y * w2 + b.y;
    acc.z += self.z * w2 + b.z;
    acc.w += self.w * w2 + b.w;
    acc.x = acc.x > 0.f ? acc.x : 0.01f * acc.x;
    acc.y = acc.y > 0.f ? acc.y : 0.01f * acc.y;
    acc.z = acc.z > 0.f ? acc.z : 0.01f * acc.z;
    acc.w = acc.w > 0.f ? acc.w : 0.01f * acc.w;
    *((float4*)(out + (size_t)node * ldc) + lane) = acc;
}

// ---------------- final: s_ci = sigmoid(s @ Wl2 + bl2), replicate x3 ----------------
__global__ __launch_bounds__(256) void rowdot_sigmoid(
    const float* __restrict__ s, const float* __restrict__ w, const float* __restrict__ b,
    float* __restrict__ out, int n)
{
    int row = blockIdx.x * 4 + (threadIdx.x >> 6);
    int lane = threadIdx.x & 63;
    if (row >= n) return;
    const float4* sr = (const float4*)(s + (size_t)row * 256);
    const float4* wr = (const float4*)w;
    float4 a = sr[lane], c = wr[lane];
    float p = a.x * c.x + a.y * c.y + a.z * c.z + a.w * c.w;
#pragma unroll
    for (int off = 32; off > 0; off >>= 1) p += __shfl_down(p, off);
    if (lane == 0) {
        float v = 1.0f / (1.0f + expf(-(p + b[0])));
        out[row] = v;
        out[n + row] = v;
        out[2 * n + row] = v;
    }
}

extern "C" void kernel_launch(void* const* d_in, const int* in_sizes, int n_in,
                              void* d_out, int out_size, void* d_ws, size_t ws_size,
                              hipStream_t stream)
{
    const float* discrete_x = (const float*)d_in[0];
    const float* continous_x = (const float*)d_in[1];
    const float* Wd  = (const float*)d_in[2];  const float* bd  = (const float*)d_in[3];
    const float* Wc1 = (const float*)d_in[4];  const float* bc1 = (const float*)d_in[5];
    const float* Wc2 = (const float*)d_in[6];  const float* bc2 = (const float*)d_in[7];
    const float* Wg0 = (const float*)d_in[8];  const float* bg0 = (const float*)d_in[9];
    const float* Wg1 = (const float*)d_in[10]; const float* bg1 = (const float*)d_in[11];
    const float* Wg2 = (const float*)d_in[12]; const float* bg2 = (const float*)d_in[13];
    const float* Wf  = (const float*)d_in[14]; const float* bf  = (const float*)d_in[15];
    const float* Wl1 = (const float*)d_in[16]; const float* bl1 = (const float*)d_in[17];
    const float* Wl2 = (const float*)d_in[18]; const float* bl2 = (const float*)d_in[19];
    const int* edge_index = (const int*)d_in[20];
    const int* src = edge_index;
    const int* dst = edge_index + NEDGES;

    float* out = (float*)d_out;
    float* ws = (float*)d_ws;

    // workspace layout (floats; keep 16B alignment everywhere)
    float* dinv       = ws;                                    // 50048
    int*   deg        = (int*)(ws + 50048);                    // 50048
    int*   rowptr     = (int*)(ws + 2 * 50048);                // 50048+64
    int*   cursor     = (int*)(ws + 3 * 50048 + 64);           // 50048
    int*   excl       = (int*)(ws + 4 * 50048 + 64);           // 50048
    int*   blocksum   = (int*)(ws + 5 * 50048 + 64);           // 64
    int*   src_sorted = (int*)(ws + 5 * 50048 + 128);          // 800000
    float* w_sorted   = ws + 5 * 50048 + 128 + NEDGES;         // 800000
    float* xcat       = w_sorted + NEDGES;                     // NNODES*1024
    float* xg         = xcat + (size_t)NNODES * 1024;          // NNODES*256
    float* tbuf       = xg   + (size_t)NNODES * EMB;           // NNODES*256
    float* sbuf       = tbuf + (size_t)NNODES * EMB;           // NNODES*256

    float* h_out  = out + 3 * (size_t)NNODES;                  // NNODES * 512
    float* h_out2 = h_out + (size_t)NNODES * HID;

    dim3 blk(256);
    auto gemm = [&](const float* A, int lda, const float* B, int ldb, float* C, int ldc,
                    float* C2, const float* bias, int M, int N, int K, int act) {
        dim3 grid((N + BN - 1) / BN, (M + BM - 1) / BM);
        hipLaunchKernelGGL(gemm_kernel, grid, blk, 0, stream,
                           A, lda, B, ldb, C, ldc, C2, bias, M, N, K, act);
    };

    // ---- CSR build (once) + dinv ----
    hipMemsetAsync(deg, 0, NNODES * sizeof(int), stream);
    hipLaunchKernelGGL(count_deg, dim3((NEDGES + 255) / 256), blk, 0, stream, dst, deg, NEDGES);
    hipLaunchKernelGGL(dinv_kernel, dim3((NNODES + 255) / 256), blk, 0, stream, deg, dinv, NNODES);
    int nb = (NNODES + 1023) / 1024;
    hipLaunchKernelGGL(scan1, dim3(nb), blk, 0, stream, deg, excl, blocksum, NNODES);
    hipLaunchKernelGGL(scan2, dim3(1), blk, 0, stream, blocksum, nb);
    hipLaunchKernelGGL(scan3, dim3((NNODES + 255) / 256), blk, 0, stream,
                       rowptr, cursor, excl, blocksum, NNODES);
    hipLaunchKernelGGL(fill_csr, dim3((NEDGES + 255) / 256), blk, 0, stream,
                       src, dst, dinv, cursor, src_sorted, w_sorted, NEDGES);

    // ---- embeddings directly into concat buffer [N,1024] = [x_d | x_c1 | x_c2 | x_g2] --
    gemm(discrete_x,       64, Wd,  EMB, xcat + 0,   1024, nullptr, bd,  NNODES, EMB, 64, 1);
    gemm(continous_x,      39, Wc1, EMB, xcat + 256, 1024, nullptr, bc1, NNODES, EMB, 13, 1);
    gemm(continous_x + 13, 39, Wc2, EMB, xcat + 512, 1024, nullptr, bc2, NNODES, EMB, 13, 1);
    gemm(discrete_x,       64, Wg0, EMB, xg,          EMB, nullptr, bg0, NNODES, EMB, 64, 1);

    // ---- GCN conv 1: t = xg@Wg1; xg = lrelu(gather(t) + t*dinv^2 + bg1) ----
    gemm(xg, EMB, Wg1, EMB, tbuf, EMB, nullptr, nullptr, NNODES, EMB, EMB, 0);
    hipLaunchKernelGGL(gather_conv, dim3((NNODES + 3) / 4), blk, 0, stream,
                       tbuf, rowptr, src_sorted, w_sorted, dinv, bg1, xg, EMB);

    // ---- GCN conv 2 -> write into concat column 768 ----
    gemm(xg, EMB, Wg2, EMB, tbuf, EMB, nullptr, nullptr, NNODES, EMB, EMB, 0);
    hipLaunchKernelGGL(gather_conv, dim3((NNODES + 3) / 4), blk, 0, stream,
                       tbuf, rowptr, src_sorted, w_sorted, dinv, bg2, xcat + 768, 1024);

    // ---- h_ci = lrelu(xcat @ Wf + bf) -> directly into both d_out slots ----
    gemm(xcat, 1024, Wf, HID, h_out, HID, h_out2, bf, NNODES, HID, 1024, 1);

    // ---- s = lrelu(h @ Wl1 + bl1) ----
    gemm(h_out, HID, Wl1, 256, sbuf, 256, nullptr, bl1, NNODES, 256, HID, 1);

    // ---- s_ci = sigmoid(s @ Wl2 + bl2) -> out[0:N], out[N:2N], out[2N:3N] ----
    hipLaunchKernelGGL(rowdot_sigmoid, dim3((NNODES + 3) / 4), blk, 0, stream,
                       sbuf, Wl2, bl2, out, NNODES);
}